// Round 6
// baseline (115.953 us; speedup 1.0000x reference)
//
#include <hip/hip_runtime.h>
#include <cstdint>

// NT-Xent: B=4096, D=128, N=8192, T=0.5
// loss = mean_i( log(sum_{j!=i} exp(sim_ij/T)) - sim_{i,(i+B)%N}/T )
//
// R5 -> R6: abandon the global-direct inner loop (3 rounds of regalloc
// fighting, all 41.5us, ~85% latency stall). Verified m97-family structure:
//  - 8-wave block, 128 rows x 1024 cols; wave = 32 rows (A = 32 VGPR only)
//    x 64-col half-panel
//  - B panels in LDS, double-buffered, reg-staged (T14 split), XOR-swizzled
//    (G4: [col][256B] rows are 16-way conflicts otherwise)
//  - hot loop reads are ds_read_b128 only; global latency only on prefetch

#define BROWS 4096
#define NROWS 8192
#define ROWB  256          // bytes per bf16 row (128 * 2)
#define CSPL  8            // column splits (grid.y)
#define NP    8            // panels per block (1024 cols / 128)
#define PCOLS 128          // cols per panel
#define PBYTES (PCOLS * ROWB)   // 32 KB per panel buffer
#define PARTS (CSPL * 2)   // partial slots: colsplit x colhalf

typedef __attribute__((ext_vector_type(8))) __bf16    bf16x8;
typedef __attribute__((ext_vector_type(4))) float     f32x4;
typedef __attribute__((ext_vector_type(4))) uint32_t  u32x4;

#define K1F 2.8853900817779268f   // (1/T)*log2(e)
#define LN2F 0.69314718055994531f
#define BC8(x) __builtin_bit_cast(bf16x8, x)

__device__ __forceinline__ uint16_t f2bf(float f) {
    uint32_t u = __builtin_bit_cast(uint32_t, f);
    u = (u + 0x7FFFu + ((u >> 16) & 1u)) >> 16;
    return (uint16_t)u;
}
__device__ __forceinline__ float bf2f(uint16_t b) {
    return __builtin_bit_cast(float, ((uint32_t)b) << 16);
}

// ---- kernel 1: L2-normalize rows; emit znB = bf16(x^), znA = bf16(K1*x^) ----
__global__ __launch_bounds__(256) void k_normalize(
    const float* __restrict__ zi, const float* __restrict__ zj,
    uint16_t* __restrict__ znA, uint16_t* __restrict__ znB)
{
    int tid  = threadIdx.x;
    int lane = tid & 63;
    int wid  = tid >> 6;
    int li   = lane & 7;
    int row  = blockIdx.x * 32 + wid * 8 + (lane >> 3);

    const float* src = (row < BROWS) ? (zi + (size_t)row * 128)
                                     : (zj + (size_t)(row - BROWS) * 128);
    float4 v[4];
    const float4* s4 = (const float4*)(src + li * 16);
#pragma unroll
    for (int c = 0; c < 4; ++c) v[c] = s4[c];

    float ss = 0.f;
#pragma unroll
    for (int c = 0; c < 4; ++c)
        ss += v[c].x*v[c].x + v[c].y*v[c].y + v[c].z*v[c].z + v[c].w*v[c].w;
#pragma unroll
    for (int off = 1; off < 8; off <<= 1) ss += __shfl_xor(ss, off);

    float scale = 1.0f / fmaxf(sqrtf(ss), 1e-8f);

    float e[16];
#pragma unroll
    for (int c = 0; c < 4; ++c) {
        e[c*4+0] = v[c].x * scale; e[c*4+1] = v[c].y * scale;
        e[c*4+2] = v[c].z * scale; e[c*4+3] = v[c].w * scale;
    }
    uint32_t wB[8], wA[8];
#pragma unroll
    for (int q = 0; q < 8; ++q) {
        wB[q] = (uint32_t)f2bf(e[2*q])       | ((uint32_t)f2bf(e[2*q+1])       << 16);
        wA[q] = (uint32_t)f2bf(e[2*q] * K1F) | ((uint32_t)f2bf(e[2*q+1] * K1F) << 16);
    }
    uint4* dB = (uint4*)((char*)znB + (size_t)row * ROWB + li * 32);
    dB[0] = make_uint4(wB[0], wB[1], wB[2], wB[3]);
    dB[1] = make_uint4(wB[4], wB[5], wB[6], wB[7]);
    uint4* dA = (uint4*)((char*)znA + (size_t)row * ROWB + li * 32);
    dA[0] = make_uint4(wA[0], wA[1], wA[2], wA[3]);
    dA[1] = make_uint4(wA[4], wA[5], wA[6], wA[7]);
}

// ---- kernel 2: LDS-staged MFMA + sum(exp) per row ---------------------------
// grid (64 rowblocks, 8 colsplits); block 512 thr = 8 waves.
// Wave w: rows = bx*128 + (w>>1)*32 (2 rt of 16), colhalf h = w&1 (64 cols).
__global__ __launch_bounds__(512)
__attribute__((amdgpu_waves_per_eu(4, 4)))
void k_simlse(
    const uint16_t* __restrict__ znA, const uint16_t* __restrict__ znB,
    float* __restrict__ partial)
{
    __shared__ __align__(16) char lds[2][PBYTES];   // 64 KB double buffer

    const char* zA = (const char*)znA;
    const char* zB = (const char*)znB;
    int tid  = threadIdx.x;
    int lane = tid & 63;
    int wid  = tid >> 6;        // 0..7
    int lo16 = lane & 15;
    int hi4  = lane >> 4;       // 0..3
    int h    = wid & 1;         // col half
    int pB   = wid >> 1;        // row-pair index 0..3
    int rowBase = blockIdx.x * 128 + pB * 32;
    int colBase = blockIdx.y * (NP * PCOLS);
    int xorv = (lo16 & 7) << 4; // read-side swizzle (pc&7 == lo16&7)

    // A fragments (prescaled by K1): 2 row-tiles x 4 K-frags = 32 VGPR.
    u32x4 a[2][4];
#pragma unroll
    for (int rt = 0; rt < 2; ++rt) {
        const char* ap = zA + (size_t)(rowBase + rt * 16 + lo16) * ROWB + hi4 * 16;
#pragma unroll
        for (int kf = 0; kf < 4; ++kf)
            a[rt][kf] = *(const u32x4*)(ap + kf * 64);
    }

    float rs[2][4];
#pragma unroll
    for (int rt = 0; rt < 2; ++rt)
#pragma unroll
        for (int r = 0; r < 4; ++r) rs[rt][r] = 0.f;

    // ---- staging helpers: 512 thr x 4 x 16B = 32 KB panel ----
#define STAGE_LOAD(sreg, p) do {                                              \
        const char* gb_ = zB + (size_t)(colBase + (p) * PCOLS) * ROWB;        \
        _Pragma("unroll")                                                     \
        for (int i_ = 0; i_ < 4; ++i_)                                        \
            sreg[i_] = *(const u32x4*)(gb_ + (size_t)(i_ * 512 + tid) * 16);  \
    } while (0)

#define STAGE_WRITE(bsel, sreg) do {                                          \
        _Pragma("unroll")                                                     \
        for (int i_ = 0; i_ < 4; ++i_) {                                      \
            int slot_ = i_ * 512 + tid;                                       \
            int row_ = slot_ >> 4, ci_ = slot_ & 15;                          \
            *(u32x4*)(&lds[bsel][row_ * 256 + ((ci_ * 16) ^ ((row_ & 7) << 4))]) = sreg[i_]; \
        }                                                                     \
    } while (0)

#define COMPUTE(bsel) do {                                                    \
        const char* lb_ = &lds[bsel][0] + (size_t)(h * 64 + lo16) * 256;      \
        _Pragma("unroll")                                                     \
        for (int ct = 0; ct < 4; ++ct) {                                      \
            u32x4 bf[4];                                                      \
            _Pragma("unroll")                                                 \
            for (int kf = 0; kf < 4; ++kf)                                    \
                bf[kf] = *(const u32x4*)(lb_ + ct * 16 * 256                  \
                              + ((kf * 64 + hi4 * 16) ^ xorv));               \
            _Pragma("unroll")                                                 \
            for (int rt = 0; rt < 2; ++rt) {                                  \
                f32x4 acc = {0.f, 0.f, 0.f, 0.f};                             \
                _Pragma("unroll")                                             \
                for (int kf = 0; kf < 4; ++kf)                                \
                    acc = __builtin_amdgcn_mfma_f32_16x16x32_bf16(            \
                            BC8(a[rt][kf]), BC8(bf[kf]), acc, 0, 0, 0);       \
                _Pragma("unroll")                                             \
                for (int r = 0; r < 4; ++r)                                   \
                    rs[rt][r] += __builtin_amdgcn_exp2f(acc[r]);              \
            }                                                                 \
        }                                                                     \
    } while (0)

    // prologue: stage panel 0
    {
        u32x4 s0[4];
        STAGE_LOAD(s0, 0);
        STAGE_WRITE(0, s0);
    }
    __syncthreads();

    for (int p = 0; p < NP; ++p) {
        u32x4 sn[4];
        if (p + 1 < NP) STAGE_LOAD(sn, p + 1);   // prefetch overlaps compute
        COMPUTE(p & 1);
        __syncthreads();                          // everyone done reading other buf
        if (p + 1 < NP) STAGE_WRITE((p + 1) & 1, sn);
        __syncthreads();                          // writes visible
    }

#undef STAGE_LOAD
#undef STAGE_WRITE
#undef COMPUTE

    // reduce row-sums across the 16 column-lanes; write per-(split,half) partials
#pragma unroll
    for (int rt = 0; rt < 2; ++rt)
#pragma unroll
        for (int r = 0; r < 4; ++r) {
            float s = rs[rt][r];
            s += __shfl_xor(s, 1);  s += __shfl_xor(s, 2);
            s += __shfl_xor(s, 4);  s += __shfl_xor(s, 8);
            if (lo16 == 0) {
                int row = rowBase + rt * 16 + hi4 * 4 + r;
                partial[(blockIdx.y * 2 + h) * NROWS + row] = s;
            }
        }
}

// ---- kernel 3: per-row lse - pos, subtract diag, block partial sums --------
__global__ __launch_bounds__(256) void k_finalize(
    const uint16_t* __restrict__ znA, const uint16_t* __restrict__ znB,
    const float* __restrict__ partial, float* __restrict__ blocksum)
{
    int tid = threadIdx.x;
    int i = blockIdx.x * 256 + tid;

    float S = 0.f;
#pragma unroll
    for (int cs = 0; cs < PARTS; ++cs) S += partial[cs * NROWS + i];

    int j = (i + BROWS) & (NROWS - 1);
    const uint4* rAi = (const uint4*)((const char*)znA + (size_t)i * ROWB);
    const uint4* rBi = (const uint4*)((const char*)znB + (size_t)i * ROWB);
    const uint4* rBj = (const uint4*)((const char*)znB + (size_t)j * ROWB);
    float adot = 0.f;   // K1 * <zn_i, zn_j>
    float sdot = 0.f;   // K1 * <zn_i, zn_i>
#pragma unroll
    for (int c = 0; c < 16; ++c) {
        uint4 ua = rAi[c], ub = rBi[c], vb = rBj[c];
        const uint32_t* pa = (const uint32_t*)&ua;
        const uint32_t* pb = (const uint32_t*)&ub;
        const uint32_t* pv = (const uint32_t*)&vb;
#pragma unroll
        for (int q = 0; q < 4; ++q) {
            float a0 = bf2f((uint16_t)(pa[q] & 0xffffu)), a1 = bf2f((uint16_t)(pa[q] >> 16));
            float b0 = bf2f((uint16_t)(pb[q] & 0xffffu)), b1 = bf2f((uint16_t)(pb[q] >> 16));
            float v0 = bf2f((uint16_t)(pv[q] & 0xffffu)), v1 = bf2f((uint16_t)(pv[q] >> 16));
            adot += a0 * v0 + a1 * v1;
            sdot += a0 * b0 + a1 * b1;
        }
    }
    S -= __builtin_amdgcn_exp2f(sdot);                  // remove diagonal term
    float c = LN2F * (__builtin_amdgcn_logf(S) - adot); // ln(S) - pos/T

#pragma unroll
    for (int off = 1; off < 64; off <<= 1) c += __shfl_xor(c, off);
    __shared__ float wsum[4];
    int lane = tid & 63, wid = tid >> 6;
    if (lane == 0) wsum[wid] = c;
    __syncthreads();
    if (tid == 0) blocksum[blockIdx.x] = wsum[0] + wsum[1] + wsum[2] + wsum[3];
}

// ---- kernel 4: final scalar -------------------------------------------------
__global__ __launch_bounds__(64) void k_reduce(
    const float* __restrict__ blocksum, float* __restrict__ out)
{
    int tid = threadIdx.x;
    float v = (tid < 32) ? blocksum[tid] : 0.f;
#pragma unroll
    for (int off = 1; off < 64; off <<= 1) v += __shfl_xor(v, off);
    if (tid == 0) out[0] = v * (1.0f / (float)NROWS);
}

extern "C" void kernel_launch(void* const* d_in, const int* in_sizes, int n_in,
                              void* d_out, int out_size, void* d_ws, size_t ws_size,
                              hipStream_t stream)
{
    const float* zi = (const float*)d_in[0];
    const float* zj = (const float*)d_in[1];
    float* out = (float*)d_out;

    char* ws = (char*)d_ws;
    uint16_t* znA      = (uint16_t*)ws;                                   // 2 MB
    uint16_t* znB      = (uint16_t*)(ws + (size_t)NROWS * ROWB);          // 2 MB
    float*    partial  = (float*)(ws + 2 * (size_t)NROWS * ROWB);         // 512 KB
    float*    blocksum = (float*)(ws + 2 * (size_t)NROWS * ROWB
                                     + (size_t)PARTS * NROWS * 4);

    k_normalize<<<dim3(256), dim3(256), 0, stream>>>(zi, zj, znA, znB);
    k_simlse  <<<dim3(64, CSPL), dim3(512), 0, stream>>>(znA, znB, partial);
    k_finalize<<<dim3(32), dim3(256), 0, stream>>>(znA, znB, partial, blocksum);
    k_reduce  <<<dim3(1), dim3(64), 0, stream>>>(blocksum, out);
}

// Round 7
// 56.836 us; speedup vs baseline: 2.0401x; 2.0401x over previous
//
#include <hip/hip_runtime.h>
#include <cstdint>

// NT-Xent: B=4096, D=128, N=8192, T=0.5
// loss = mean_i( log(sum_{j!=i} exp(sim_ij/T)) - sim_{i,(i+B)%N}/T )
//
// R6 -> R7: revert LDS (real spills). Re-read of R3-R5 counters: A lives in
// AGPRs (no scratch traffic; 76 VGPR + 64 AGPR = 3 waves/SIMD) -- regalloc was
// never the problem. New theory: serial MFMA accumulator chains (4 dependent
// mfma per rt) + exp waiting on the last link = the stall.
//  - kf-outer / rt-inner: 4 independent acc chains, same math
//  - B prefetch ring deepened to 3 (covers ~2 compute phases ~ L3 latency)
//  - asm pins removed (proven neutral)

#define BROWS 4096
#define NROWS 8192
#define ROWB  256          // bytes per bf16 row
#define CSPL  24           // column splits: 32 rowblocks x 24 = 768 blocks
#define CTILES 512         // 8192/16 column tiles
#define BRT   256          // rows per block (4 waves x 64)

typedef __attribute__((ext_vector_type(8))) __bf16    bf16x8;
typedef __attribute__((ext_vector_type(4))) float     f32x4;
typedef __attribute__((ext_vector_type(4))) uint32_t  u32x4;

#define K1F 2.8853900817779268f   // (1/T)*log2(e)
#define LN2F 0.69314718055994531f
#define BC8(x) __builtin_bit_cast(bf16x8, x)

__device__ __forceinline__ uint16_t f2bf(float f) {
    uint32_t u = __builtin_bit_cast(uint32_t, f);
    u = (u + 0x7FFFu + ((u >> 16) & 1u)) >> 16;
    return (uint16_t)u;
}
__device__ __forceinline__ float bf2f(uint16_t b) {
    return __builtin_bit_cast(float, ((uint32_t)b) << 16);
}

// ---- kernel 1: L2-normalize rows; emit znB = bf16(x^), znA = bf16(K1*x^) ----
__global__ __launch_bounds__(256) void k_normalize(
    const float* __restrict__ zi, const float* __restrict__ zj,
    uint16_t* __restrict__ znA, uint16_t* __restrict__ znB)
{
    int tid  = threadIdx.x;
    int lane = tid & 63;
    int wid  = tid >> 6;
    int li   = lane & 7;
    int row  = blockIdx.x * 32 + wid * 8 + (lane >> 3);

    const float* src = (row < BROWS) ? (zi + (size_t)row * 128)
                                     : (zj + (size_t)(row - BROWS) * 128);
    float4 v[4];
    const float4* s4 = (const float4*)(src + li * 16);
#pragma unroll
    for (int c = 0; c < 4; ++c) v[c] = s4[c];

    float ss = 0.f;
#pragma unroll
    for (int c = 0; c < 4; ++c)
        ss += v[c].x*v[c].x + v[c].y*v[c].y + v[c].z*v[c].z + v[c].w*v[c].w;
#pragma unroll
    for (int off = 1; off < 8; off <<= 1) ss += __shfl_xor(ss, off);

    float scale = 1.0f / fmaxf(sqrtf(ss), 1e-8f);

    float e[16];
#pragma unroll
    for (int c = 0; c < 4; ++c) {
        e[c*4+0] = v[c].x * scale; e[c*4+1] = v[c].y * scale;
        e[c*4+2] = v[c].z * scale; e[c*4+3] = v[c].w * scale;
    }
    uint32_t wB[8], wA[8];
#pragma unroll
    for (int q = 0; q < 8; ++q) {
        wB[q] = (uint32_t)f2bf(e[2*q])       | ((uint32_t)f2bf(e[2*q+1])       << 16);
        wA[q] = (uint32_t)f2bf(e[2*q] * K1F) | ((uint32_t)f2bf(e[2*q+1] * K1F) << 16);
    }
    uint4* dB = (uint4*)((char*)znB + (size_t)row * ROWB + li * 32);
    dB[0] = make_uint4(wB[0], wB[1], wB[2], wB[3]);
    dB[1] = make_uint4(wB[4], wB[5], wB[6], wB[7]);
    uint4* dA = (uint4*)((char*)znA + (size_t)row * ROWB + li * 32);
    dA[0] = make_uint4(wA[0], wA[1], wA[2], wA[3]);
    dA[1] = make_uint4(wA[4], wA[5], wA[6], wA[7]);
}

// ---- kernel 2: sim tiles via MFMA + sum(exp) per row ------------------------
// grid (32 rowblocks, 24 colsplits) = 768 blocks = 3/CU, fully resident.
__global__ __launch_bounds__(256)
__attribute__((amdgpu_waves_per_eu(3, 3)))
void k_simlse(
    const uint16_t* __restrict__ znA, const uint16_t* __restrict__ znB,
    float* __restrict__ partial)
{
    const char* zA = (const char*)znA;
    const char* zB = (const char*)znB;
    int tid  = threadIdx.x;
    int lane = tid & 63;
    int wid  = tid >> 6;
    int lo16 = lane & 15;
    int hi4  = lane >> 4;
    int rowBase = blockIdx.x * BRT + wid * 64;

    // A fragments (prescaled by K1): 4 row-tiles x 4 K-frags = 64 regs (AGPR-able).
    u32x4 a[4][4];
#pragma unroll
    for (int rt = 0; rt < 4; ++rt) {
        const char* ap = zA + (size_t)(rowBase + rt * 16 + lo16) * ROWB + hi4 * 16;
#pragma unroll
        for (int kf = 0; kf < 4; ++kf)
            a[rt][kf] = *(const u32x4*)(ap + kf * 64);
    }

    float rs[4][4];
#pragma unroll
    for (int rt = 0; rt < 4; ++rt)
#pragma unroll
        for (int r = 0; r < 4; ++r) rs[rt][r] = 0.f;

    // ragged col-tile range for this split (21 or 22 tiles)
    int t0 = (CTILES * blockIdx.y) / CSPL;
    int t1 = (CTILES * (blockIdx.y + 1)) / CSPL;
    int nt = t1 - t0;

    const char* bbase = zB + (size_t)(t0 * 16 + lo16) * ROWB + hi4 * 16;

#define LOADB(buf, t) do { const char* p_ = bbase + (size_t)(t) * (16 * ROWB); \
        buf[0] = *(const u32x4*)(p_);       buf[1] = *(const u32x4*)(p_ + 64);  \
        buf[2] = *(const u32x4*)(p_ + 128); buf[3] = *(const u32x4*)(p_ + 192); } while (0)

    // kf-outer / rt-inner: 4 independent accumulator chains; exps batched.
#define COMPUTE(buf) do {                                                        \
        f32x4 ac0 = {0.f,0.f,0.f,0.f}, ac1 = {0.f,0.f,0.f,0.f};                  \
        f32x4 ac2 = {0.f,0.f,0.f,0.f}, ac3 = {0.f,0.f,0.f,0.f};                  \
        _Pragma("unroll")                                                        \
        for (int kf = 0; kf < 4; ++kf) {                                         \
            bf16x8 bk_ = BC8(buf[kf]);                                           \
            ac0 = __builtin_amdgcn_mfma_f32_16x16x32_bf16(BC8(a[0][kf]), bk_, ac0, 0, 0, 0); \
            ac1 = __builtin_amdgcn_mfma_f32_16x16x32_bf16(BC8(a[1][kf]), bk_, ac1, 0, 0, 0); \
            ac2 = __builtin_amdgcn_mfma_f32_16x16x32_bf16(BC8(a[2][kf]), bk_, ac2, 0, 0, 0); \
            ac3 = __builtin_amdgcn_mfma_f32_16x16x32_bf16(BC8(a[3][kf]), bk_, ac3, 0, 0, 0); \
        }                                                                        \
        _Pragma("unroll")                                                        \
        for (int r = 0; r < 4; ++r) {                                            \
            rs[0][r] += __builtin_amdgcn_exp2f(ac0[r]);                          \
            rs[1][r] += __builtin_amdgcn_exp2f(ac1[r]);                          \
            rs[2][r] += __builtin_amdgcn_exp2f(ac2[r]);                          \
            rs[3][r] += __builtin_amdgcn_exp2f(ac3[r]);                          \
        }                                                                        \
    } while (0)

    u32x4 b0[4], b1[4], b2[4];
    LOADB(b0, 0);          // nt >= 21 always
    LOADB(b1, 1);
    LOADB(b2, 2);

    int t = 0;
    for (; t + 3 < nt; t += 3) {
        COMPUTE(b0); LOADB(b0, t + 3);
        COMPUTE(b1); LOADB(b1, (t + 4 < nt) ? t + 4 : nt - 1);
        COMPUTE(b2); LOADB(b2, (t + 5 < nt) ? t + 5 : nt - 1);
    }
    COMPUTE(b0);
    if (t + 1 < nt) COMPUTE(b1);
    if (t + 2 < nt) COMPUTE(b2);

#undef LOADB
#undef COMPUTE

    // reduce row-sums across the 16 column-lanes; write per-split partials
#pragma unroll
    for (int rt = 0; rt < 4; ++rt)
#pragma unroll
        for (int r = 0; r < 4; ++r) {
            float s = rs[rt][r];
            s += __shfl_xor(s, 1);  s += __shfl_xor(s, 2);
            s += __shfl_xor(s, 4);  s += __shfl_xor(s, 8);
            if (lo16 == 0) {
                int row = rowBase + rt * 16 + hi4 * 4 + r;
                partial[blockIdx.y * NROWS + row] = s;
            }
        }
}

// ---- kernel 3: per-row lse - pos, subtract diag, block partial sums --------
__global__ __launch_bounds__(256) void k_finalize(
    const uint16_t* __restrict__ znA, const uint16_t* __restrict__ znB,
    const float* __restrict__ partial, float* __restrict__ blocksum)
{
    int tid = threadIdx.x;
    int i = blockIdx.x * 256 + tid;

    float S = 0.f;
#pragma unroll
    for (int cs = 0; cs < CSPL; ++cs) S += partial[cs * NROWS + i];

    int j = (i + BROWS) & (NROWS - 1);
    const uint4* rAi = (const uint4*)((const char*)znA + (size_t)i * ROWB);
    const uint4* rBi = (const uint4*)((const char*)znB + (size_t)i * ROWB);
    const uint4* rBj = (const uint4*)((const char*)znB + (size_t)j * ROWB);
    float adot = 0.f;   // K1 * <zn_i, zn_j>
    float sdot = 0.f;   // K1 * <zn_i, zn_i>
#pragma unroll
    for (int c = 0; c < 16; ++c) {
        uint4 ua = rAi[c], ub = rBi[c], vb = rBj[c];
        const uint32_t* pa = (const uint32_t*)&ua;
        const uint32_t* pb = (const uint32_t*)&ub;
        const uint32_t* pv = (const uint32_t*)&vb;
#pragma unroll
        for (int q = 0; q < 4; ++q) {
            float a0 = bf2f((uint16_t)(pa[q] & 0xffffu)), a1 = bf2f((uint16_t)(pa[q] >> 16));
            float b0 = bf2f((uint16_t)(pb[q] & 0xffffu)), b1 = bf2f((uint16_t)(pb[q] >> 16));
            float v0 = bf2f((uint16_t)(pv[q] & 0xffffu)), v1 = bf2f((uint16_t)(pv[q] >> 16));
            adot += a0 * v0 + a1 * v1;
            sdot += a0 * b0 + a1 * b1;
        }
    }
    S -= __builtin_amdgcn_exp2f(sdot);                  // remove diagonal term
    float c = LN2F * (__builtin_amdgcn_logf(S) - adot); // ln(S) - pos/T

#pragma unroll
    for (int off = 1; off < 64; off <<= 1) c += __shfl_xor(c, off);
    __shared__ float wsum[4];
    int lane = tid & 63, wid = tid >> 6;
    if (lane == 0) wsum[wid] = c;
    __syncthreads();
    if (tid == 0) blocksum[blockIdx.x] = wsum[0] + wsum[1] + wsum[2] + wsum[3];
}

// ---- kernel 4: final scalar -------------------------------------------------
__global__ __launch_bounds__(64) void k_reduce(
    const float* __restrict__ blocksum, float* __restrict__ out)
{
    int tid = threadIdx.x;
    float v = (tid < 32) ? blocksum[tid] : 0.f;
#pragma unroll
    for (int off = 1; off < 64; off <<= 1) v += __shfl_xor(v, off);
    if (tid == 0) out[0] = v * (1.0f / (float)NROWS);
}

extern "C" void kernel_launch(void* const* d_in, const int* in_sizes, int n_in,
                              void* d_out, int out_size, void* d_ws, size_t ws_size,
                              hipStream_t stream)
{
    const float* zi = (const float*)d_in[0];
    const float* zj = (const float*)d_in[1];
    float* out = (float*)d_out;

    char* ws = (char*)d_ws;
    uint16_t* znA      = (uint16_t*)ws;                                   // 2 MB
    uint16_t* znB      = (uint16_t*)(ws + (size_t)NROWS * ROWB);          // 2 MB
    float*    partial  = (float*)(ws + 2 * (size_t)NROWS * ROWB);         // 768 KB
    float*    blocksum = (float*)(ws + 2 * (size_t)NROWS * ROWB
                                     + (size_t)CSPL * NROWS * 4);

    k_normalize<<<dim3(256), dim3(256), 0, stream>>>(zi, zj, znA, znB);
    k_simlse  <<<dim3(32, CSPL), dim3(256), 0, stream>>>(znA, znB, partial);
    k_finalize<<<dim3(32), dim3(256), 0, stream>>>(znA, znB, partial, blocksum);
    k_reduce  <<<dim3(1), dim3(64), 0, stream>>>(blocksum, out);
}

// Round 8
// 41.625 us; speedup vs baseline: 2.7857x; 1.3654x over previous
//
#include <hip/hip_runtime.h>
#include <cstdint>

// NT-Xent: B=4096, D=128, N=8192, T=0.5
// loss = mean_i( log(sum_{j!=i} exp(sim_ij/T)) - sim_{i,(i+B)%N}/T )
//
// R7 -> R8: only untested suspect left = in-loop global B-loads (every wave
// loads the whole 4KB tile itself; 2 waves/SIMD effective; L3 latency
// exposed). Fix with ZERO-register LDS staging:
//  - __builtin_amdgcn_global_load_lds width=16, double-buffered 2x4KB
//  - 4 waves share each B tile (global traffic /4)
//  - linear LDS dest + inverse-swizzled global SOURCE + swizzled ds_read
//    (rule 21: both-sides-or-neither; involution off ^= (row&7)<<4)
//  - rest of skeleton identical to R7 (A in regs, kf-outer chains, 1 barrier/tile)

#define BROWS 4096
#define NROWS 8192
#define ROWB  256          // bytes per bf16 row
#define CSPL  24           // column splits: 32 rowblocks x 24 = 768 blocks
#define CTILES 512         // 8192/16 column tiles
#define BRT   256          // rows per block (4 waves x 64)
#define TILEB 4096         // bytes per 16-col B tile (16 rows x 256 B)

typedef __attribute__((ext_vector_type(8))) __bf16    bf16x8;
typedef __attribute__((ext_vector_type(4))) float     f32x4;
typedef __attribute__((ext_vector_type(4))) uint32_t  u32x4;

#define K1F 2.8853900817779268f   // (1/T)*log2(e)
#define LN2F 0.69314718055994531f
#define BC8(x) __builtin_bit_cast(bf16x8, x)

__device__ __forceinline__ uint16_t f2bf(float f) {
    uint32_t u = __builtin_bit_cast(uint32_t, f);
    u = (u + 0x7FFFu + ((u >> 16) & 1u)) >> 16;
    return (uint16_t)u;
}
__device__ __forceinline__ float bf2f(uint16_t b) {
    return __builtin_bit_cast(float, ((uint32_t)b) << 16);
}
__device__ __forceinline__ void gload_lds16(const void* g, void* l) {
    __builtin_amdgcn_global_load_lds(
        (const __attribute__((address_space(1))) void*)g,
        (__attribute__((address_space(3))) void*)l, 16, 0, 0);
}

// ---- kernel 1: L2-normalize rows; emit znB = bf16(x^), znA = bf16(K1*x^) ----
__global__ __launch_bounds__(256) void k_normalize(
    const float* __restrict__ zi, const float* __restrict__ zj,
    uint16_t* __restrict__ znA, uint16_t* __restrict__ znB)
{
    int tid  = threadIdx.x;
    int lane = tid & 63;
    int wid  = tid >> 6;
    int li   = lane & 7;
    int row  = blockIdx.x * 32 + wid * 8 + (lane >> 3);

    const float* src = (row < BROWS) ? (zi + (size_t)row * 128)
                                     : (zj + (size_t)(row - BROWS) * 128);
    float4 v[4];
    const float4* s4 = (const float4*)(src + li * 16);
#pragma unroll
    for (int c = 0; c < 4; ++c) v[c] = s4[c];

    float ss = 0.f;
#pragma unroll
    for (int c = 0; c < 4; ++c)
        ss += v[c].x*v[c].x + v[c].y*v[c].y + v[c].z*v[c].z + v[c].w*v[c].w;
#pragma unroll
    for (int off = 1; off < 8; off <<= 1) ss += __shfl_xor(ss, off);

    float scale = 1.0f / fmaxf(sqrtf(ss), 1e-8f);

    float e[16];
#pragma unroll
    for (int c = 0; c < 4; ++c) {
        e[c*4+0] = v[c].x * scale; e[c*4+1] = v[c].y * scale;
        e[c*4+2] = v[c].z * scale; e[c*4+3] = v[c].w * scale;
    }
    uint32_t wB[8], wA[8];
#pragma unroll
    for (int q = 0; q < 8; ++q) {
        wB[q] = (uint32_t)f2bf(e[2*q])       | ((uint32_t)f2bf(e[2*q+1])       << 16);
        wA[q] = (uint32_t)f2bf(e[2*q] * K1F) | ((uint32_t)f2bf(e[2*q+1] * K1F) << 16);
    }
    uint4* dB = (uint4*)((char*)znB + (size_t)row * ROWB + li * 32);
    dB[0] = make_uint4(wB[0], wB[1], wB[2], wB[3]);
    dB[1] = make_uint4(wB[4], wB[5], wB[6], wB[7]);
    uint4* dA = (uint4*)((char*)znA + (size_t)row * ROWB + li * 32);
    dA[0] = make_uint4(wA[0], wA[1], wA[2], wA[3]);
    dA[1] = make_uint4(wA[4], wA[5], wA[6], wA[7]);
}

// ---- kernel 2: LDS-staged (gload_lds) MFMA + sum(exp) per row ---------------
// grid (32 rowblocks, 24 colsplits) = 768 blocks = 3/CU.
__global__ __launch_bounds__(256)
__attribute__((amdgpu_waves_per_eu(3, 3)))
void k_simlse(
    const uint16_t* __restrict__ znA, const uint16_t* __restrict__ znB,
    float* __restrict__ partial)
{
    __shared__ __align__(16) char lds[2][TILEB];   // 8 KB double buffer

    const char* zA = (const char*)znA;
    const char* zB = (const char*)znB;
    int tid  = threadIdx.x;
    int lane = tid & 63;
    int wid  = tid >> 6;
    int lo16 = lane & 15;
    int hi4  = lane >> 4;
    int rowBase = blockIdx.x * BRT + wid * 64;

    // A fragments (prescaled by K1): 4 row-tiles x 4 K-frags = 64 regs.
    u32x4 a[4][4];
#pragma unroll
    for (int rt = 0; rt < 4; ++rt) {
        const char* ap = zA + (size_t)(rowBase + rt * 16 + lo16) * ROWB + hi4 * 16;
#pragma unroll
        for (int kf = 0; kf < 4; ++kf)
            a[rt][kf] = *(const u32x4*)(ap + kf * 64);
    }

    float rs[4][4];
#pragma unroll
    for (int rt = 0; rt < 4; ++rt)
#pragma unroll
        for (int r = 0; r < 4; ++r) rs[rt][r] = 0.f;

    // ragged col-tile range for this split (21 or 22 tiles)
    int t0 = (CTILES * blockIdx.y) / CSPL;
    int t1 = (CTILES * (blockIdx.y + 1)) / CSPL;
    int nt = t1 - t0;

    // staging: thread tid owns LDS slot tid*16 (row=tid>>4, cir=tid&15).
    // inverse-swizzled SOURCE so that swizzled READ retrieves linear data:
    //   src_off = (tid*16) ^ (((tid>>4)&7)<<4)   [involution within rows]
    const char* gsrc = zB + (size_t)t0 * TILEB
                     + ((tid * 16) ^ (((tid >> 4) & 7) << 4));
    // wave-uniform LDS dest base: HW writes base + lane*16
    char* ldst[2] = { &lds[0][wid * 1024], &lds[1][wid * 1024] };
    int  xorv = (lo16 & 7) << 4;       // read-side swizzle

#define STAGE(sel, t) gload_lds16(gsrc + (size_t)(t) * TILEB, ldst[sel])

#define COMPUTE(sel) do {                                                        \
        const char* lb_ = &lds[sel][lo16 * 256];                                 \
        u32x4 bf[4];                                                             \
        _Pragma("unroll")                                                        \
        for (int kf = 0; kf < 4; ++kf)                                           \
            bf[kf] = *(const u32x4*)(lb_ + ((hi4 * 16 + kf * 64) ^ xorv));       \
        f32x4 ac0 = {0.f,0.f,0.f,0.f}, ac1 = {0.f,0.f,0.f,0.f};                  \
        f32x4 ac2 = {0.f,0.f,0.f,0.f}, ac3 = {0.f,0.f,0.f,0.f};                  \
        _Pragma("unroll")                                                        \
        for (int kf = 0; kf < 4; ++kf) {                                         \
            bf16x8 bk_ = BC8(bf[kf]);                                            \
            ac0 = __builtin_amdgcn_mfma_f32_16x16x32_bf16(BC8(a[0][kf]), bk_, ac0, 0, 0, 0); \
            ac1 = __builtin_amdgcn_mfma_f32_16x16x32_bf16(BC8(a[1][kf]), bk_, ac1, 0, 0, 0); \
            ac2 = __builtin_amdgcn_mfma_f32_16x16x32_bf16(BC8(a[2][kf]), bk_, ac2, 0, 0, 0); \
            ac3 = __builtin_amdgcn_mfma_f32_16x16x32_bf16(BC8(a[3][kf]), bk_, ac3, 0, 0, 0); \
        }                                                                        \
        _Pragma("unroll")                                                        \
        for (int r = 0; r < 4; ++r) {                                            \
            rs[0][r] += __builtin_amdgcn_exp2f(ac0[r]);                          \
            rs[1][r] += __builtin_amdgcn_exp2f(ac1[r]);                          \
            rs[2][r] += __builtin_amdgcn_exp2f(ac2[r]);                          \
            rs[3][r] += __builtin_amdgcn_exp2f(ac3[r]);                          \
        }                                                                        \
    } while (0)

    STAGE(0, 0);
    __syncthreads();                    // drains vmcnt: buf0 ready

    for (int t = 0; t < nt; ++t) {
        if (t + 1 < nt) STAGE((t + 1) & 1, t + 1);   // overlaps compute below
        COMPUTE(t & 1);
        __syncthreads();                // all reads done + next buf landed
    }

#undef STAGE
#undef COMPUTE

    // reduce row-sums across the 16 column-lanes; write per-split partials
#pragma unroll
    for (int rt = 0; rt < 4; ++rt)
#pragma unroll
        for (int r = 0; r < 4; ++r) {
            float s = rs[rt][r];
            s += __shfl_xor(s, 1);  s += __shfl_xor(s, 2);
            s += __shfl_xor(s, 4);  s += __shfl_xor(s, 8);
            if (lo16 == 0) {
                int row = rowBase + rt * 16 + hi4 * 4 + r;
                partial[blockIdx.y * NROWS + row] = s;
            }
        }
}

// ---- kernel 3: per-row lse - pos, subtract diag, block partial sums --------
__global__ __launch_bounds__(256) void k_finalize(
    const uint16_t* __restrict__ znA, const uint16_t* __restrict__ znB,
    const float* __restrict__ partial, float* __restrict__ blocksum)
{
    int tid = threadIdx.x;
    int i = blockIdx.x * 256 + tid;

    float S = 0.f;
#pragma unroll
    for (int cs = 0; cs < CSPL; ++cs) S += partial[cs * NROWS + i];

    int j = (i + BROWS) & (NROWS - 1);
    const uint4* rAi = (const uint4*)((const char*)znA + (size_t)i * ROWB);
    const uint4* rBi = (const uint4*)((const char*)znB + (size_t)i * ROWB);
    const uint4* rBj = (const uint4*)((const char*)znB + (size_t)j * ROWB);
    float adot = 0.f;   // K1 * <zn_i, zn_j>
    float sdot = 0.f;   // K1 * <zn_i, zn_i>
#pragma unroll
    for (int c = 0; c < 16; ++c) {
        uint4 ua = rAi[c], ub = rBi[c], vb = rBj[c];
        const uint32_t* pa = (const uint32_t*)&ua;
        const uint32_t* pb = (const uint32_t*)&ub;
        const uint32_t* pv = (const uint32_t*)&vb;
#pragma unroll
        for (int q = 0; q < 4; ++q) {
            float a0 = bf2f((uint16_t)(pa[q] & 0xffffu)), a1 = bf2f((uint16_t)(pa[q] >> 16));
            float b0 = bf2f((uint16_t)(pb[q] & 0xffffu)), b1 = bf2f((uint16_t)(pb[q] >> 16));
            float v0 = bf2f((uint16_t)(pv[q] & 0xffffu)), v1 = bf2f((uint16_t)(pv[q] >> 16));
            adot += a0 * v0 + a1 * v1;
            sdot += a0 * b0 + a1 * b1;
        }
    }
    S -= __builtin_amdgcn_exp2f(sdot);                  // remove diagonal term
    float c = LN2F * (__builtin_amdgcn_logf(S) - adot); // ln(S) - pos/T

#pragma unroll
    for (int off = 1; off < 64; off <<= 1) c += __shfl_xor(c, off);
    __shared__ float wsum[4];
    int lane = tid & 63, wid = tid >> 6;
    if (lane == 0) wsum[wid] = c;
    __syncthreads();
    if (tid == 0) blocksum[blockIdx.x] = wsum[0] + wsum[1] + wsum[2] + wsum[3];
}

// ---- kernel 4: final scalar -------------------------------------------------
__global__ __launch_bounds__(64) void k_reduce(
    const float* __restrict__ blocksum, float* __restrict__ out)
{
    int tid = threadIdx.x;
    float v = (tid < 32) ? blocksum[tid] : 0.f;
#pragma unroll
    for (int off = 1; off < 64; off <<= 1) v += __shfl_xor(v, off);
    if (tid == 0) out[0] = v * (1.0f / (float)NROWS);
}

extern "C" void kernel_launch(void* const* d_in, const int* in_sizes, int n_in,
                              void* d_out, int out_size, void* d_ws, size_t ws_size,
                              hipStream_t stream)
{
    const float* zi = (const float*)d_in[0];
    const float* zj = (const float*)d_in[1];
    float* out = (float*)d_out;

    char* ws = (char*)d_ws;
    uint16_t* znA      = (uint16_t*)ws;                                   // 2 MB
    uint16_t* znB      = (uint16_t*)(ws + (size_t)NROWS * ROWB);          // 2 MB
    float*    partial  = (float*)(ws + 2 * (size_t)NROWS * ROWB);         // 768 KB
    float*    blocksum = (float*)(ws + 2 * (size_t)NROWS * ROWB
                                     + (size_t)CSPL * NROWS * 4);

    k_normalize<<<dim3(256), dim3(256), 0, stream>>>(zi, zj, znA, znB);
    k_simlse  <<<dim3(32, CSPL), dim3(256), 0, stream>>>(znA, znB, partial);
    k_finalize<<<dim3(32), dim3(256), 0, stream>>>(znA, znB, partial, blocksum);
    k_reduce  <<<dim3(1), dim3(64), 0, stream>>>(blocksum, out);
}

// Round 9
// 39.088 us; speedup vs baseline: 2.9664x; 1.0649x over previous
//
#include <hip/hip_runtime.h>
#include <cstdint>

// NT-Xent: B=4096, D=128, N=8192, T=0.5
// loss = mean_i( log(sum_{j!=i} exp(sim_ij/T)) - sim_{i,(i+B)%N}/T )
//
// R8 -> R9: R8's LDS staging was the win (k_simlse left top-5). Remaining
// stall: __syncthreads drains vmcnt(0) every tile -> waits for the prefetch
// just issued. T3+T4 fix (m201-verified with global_load_lds):
//  - 32-col tiles, triple-buffered (3 x 8KB), 2 stages in flight
//  - raw s_barrier + counted "s_waitcnt vmcnt(2)" (never 0 in main loop)
//  - sched_barrier(0) after the wait (rule 18)

#define BROWS 4096
#define NROWS 8192
#define ROWB  256          // bytes per bf16 row
#define CSPL  24           // column splits: 32 rowblocks x 24 = 768 blocks
#define CT32  256          // 8192/32 column tiles (32-col)
#define BRT   256          // rows per block (4 waves x 64)
#define TILEB 8192         // bytes per 32-col B tile

typedef __attribute__((ext_vector_type(8))) __bf16    bf16x8;
typedef __attribute__((ext_vector_type(4))) float     f32x4;
typedef __attribute__((ext_vector_type(4))) uint32_t  u32x4;

#define K1F 2.8853900817779268f   // (1/T)*log2(e)
#define LN2F 0.69314718055994531f
#define BC8(x) __builtin_bit_cast(bf16x8, x)

__device__ __forceinline__ uint16_t f2bf(float f) {
    uint32_t u = __builtin_bit_cast(uint32_t, f);
    u = (u + 0x7FFFu + ((u >> 16) & 1u)) >> 16;
    return (uint16_t)u;
}
__device__ __forceinline__ float bf2f(uint16_t b) {
    return __builtin_bit_cast(float, ((uint32_t)b) << 16);
}
__device__ __forceinline__ void gload_lds16(const void* g, void* l) {
    __builtin_amdgcn_global_load_lds(
        (const __attribute__((address_space(1))) void*)g,
        (__attribute__((address_space(3))) void*)l, 16, 0, 0);
}

// ---- kernel 1: L2-normalize rows; emit znB = bf16(x^), znA = bf16(K1*x^) ----
__global__ __launch_bounds__(256) void k_normalize(
    const float* __restrict__ zi, const float* __restrict__ zj,
    uint16_t* __restrict__ znA, uint16_t* __restrict__ znB)
{
    int tid  = threadIdx.x;
    int lane = tid & 63;
    int wid  = tid >> 6;
    int li   = lane & 7;
    int row  = blockIdx.x * 32 + wid * 8 + (lane >> 3);

    const float* src = (row < BROWS) ? (zi + (size_t)row * 128)
                                     : (zj + (size_t)(row - BROWS) * 128);
    float4 v[4];
    const float4* s4 = (const float4*)(src + li * 16);
#pragma unroll
    for (int c = 0; c < 4; ++c) v[c] = s4[c];

    float ss = 0.f;
#pragma unroll
    for (int c = 0; c < 4; ++c)
        ss += v[c].x*v[c].x + v[c].y*v[c].y + v[c].z*v[c].z + v[c].w*v[c].w;
#pragma unroll
    for (int off = 1; off < 8; off <<= 1) ss += __shfl_xor(ss, off);

    float scale = 1.0f / fmaxf(sqrtf(ss), 1e-8f);

    float e[16];
#pragma unroll
    for (int c = 0; c < 4; ++c) {
        e[c*4+0] = v[c].x * scale; e[c*4+1] = v[c].y * scale;
        e[c*4+2] = v[c].z * scale; e[c*4+3] = v[c].w * scale;
    }
    uint32_t wB[8], wA[8];
#pragma unroll
    for (int q = 0; q < 8; ++q) {
        wB[q] = (uint32_t)f2bf(e[2*q])       | ((uint32_t)f2bf(e[2*q+1])       << 16);
        wA[q] = (uint32_t)f2bf(e[2*q] * K1F) | ((uint32_t)f2bf(e[2*q+1] * K1F) << 16);
    }
    uint4* dB = (uint4*)((char*)znB + (size_t)row * ROWB + li * 32);
    dB[0] = make_uint4(wB[0], wB[1], wB[2], wB[3]);
    dB[1] = make_uint4(wB[4], wB[5], wB[6], wB[7]);
    uint4* dA = (uint4*)((char*)znA + (size_t)row * ROWB + li * 32);
    dA[0] = make_uint4(wA[0], wA[1], wA[2], wA[3]);
    dA[1] = make_uint4(wA[4], wA[5], wA[6], wA[7]);
}

// ---- kernel 2: LDS-staged MFMA + sum(exp), counted-vmcnt pipeline -----------
// grid (32 rowblocks, 24 colsplits) = 768 blocks = 3/CU.
__global__ __launch_bounds__(256)
__attribute__((amdgpu_waves_per_eu(3, 3)))
void k_simlse(
    const uint16_t* __restrict__ znA, const uint16_t* __restrict__ znB,
    float* __restrict__ partial)
{
    __shared__ __align__(16) char lds[3][TILEB];   // 24 KB triple buffer

    const char* zA = (const char*)znA;
    const char* zB = (const char*)znB;
    int tid  = threadIdx.x;
    int lane = tid & 63;
    int wid  = tid >> 6;
    int lo16 = lane & 15;
    int hi4  = lane >> 4;
    int rowBase = blockIdx.x * BRT + wid * 64;

    // A fragments (prescaled by K1): 4 row-tiles x 4 K-frags = 64 regs.
    u32x4 a[4][4];
#pragma unroll
    for (int rt = 0; rt < 4; ++rt) {
        const char* ap = zA + (size_t)(rowBase + rt * 16 + lo16) * ROWB + hi4 * 16;
#pragma unroll
        for (int kf = 0; kf < 4; ++kf)
            a[rt][kf] = *(const u32x4*)(ap + kf * 64);
    }

    float rs[4][4];
#pragma unroll
    for (int rt = 0; rt < 4; ++rt)
#pragma unroll
        for (int r = 0; r < 4; ++r) rs[rt][r] = 0.f;

    // ragged 32-col tile range for this split (10 or 11 tiles)
    int t0 = (CT32 * blockIdx.y) / CSPL;
    int t1 = (CT32 * (blockIdx.y + 1)) / CSPL;
    int nt = t1 - t0;

    // per-lane inverse-swizzled global source (slot tid covers bytes [0,4096),
    // slot tid+256 covers [4096,8192): same swizzle bits, +4096)
    const char* gsrc = zB + (size_t)t0 * TILEB
                     + ((tid * 16) ^ (((tid >> 4) & 7) << 4));
    int xorv = (lo16 & 7) << 4;        // read-side swizzle

#define STAGE(sel, t) do {                                                     \
        const char* g_ = gsrc + (size_t)(t) * TILEB;                           \
        gload_lds16(g_,        &lds[sel][wid * 1024]);                         \
        gload_lds16(g_ + 4096, &lds[sel][4096 + wid * 1024]);                  \
    } while (0)

#define COMPUTE(sel) do {                                                        \
        _Pragma("unroll")                                                        \
        for (int ct = 0; ct < 2; ++ct) {                                         \
            const char* lb_ = &lds[sel][ct * 4096 + lo16 * 256];                 \
            u32x4 bf[4];                                                         \
            _Pragma("unroll")                                                    \
            for (int kf = 0; kf < 4; ++kf)                                       \
                bf[kf] = *(const u32x4*)(lb_ + ((hi4 * 16 + kf * 64) ^ xorv));   \
            f32x4 ac0 = {0.f,0.f,0.f,0.f}, ac1 = {0.f,0.f,0.f,0.f};              \
            f32x4 ac2 = {0.f,0.f,0.f,0.f}, ac3 = {0.f,0.f,0.f,0.f};              \
            _Pragma("unroll")                                                    \
            for (int kf = 0; kf < 4; ++kf) {                                     \
                bf16x8 bk_ = BC8(bf[kf]);                                        \
                ac0 = __builtin_amdgcn_mfma_f32_16x16x32_bf16(BC8(a[0][kf]), bk_, ac0, 0, 0, 0); \
                ac1 = __builtin_amdgcn_mfma_f32_16x16x32_bf16(BC8(a[1][kf]), bk_, ac1, 0, 0, 0); \
                ac2 = __builtin_amdgcn_mfma_f32_16x16x32_bf16(BC8(a[2][kf]), bk_, ac2, 0, 0, 0); \
                ac3 = __builtin_amdgcn_mfma_f32_16x16x32_bf16(BC8(a[3][kf]), bk_, ac3, 0, 0, 0); \
            }                                                                    \
            _Pragma("unroll")                                                    \
            for (int r = 0; r < 4; ++r) {                                        \
                rs[0][r] += __builtin_amdgcn_exp2f(ac0[r]);                      \
                rs[1][r] += __builtin_amdgcn_exp2f(ac1[r]);                      \
                rs[2][r] += __builtin_amdgcn_exp2f(ac2[r]);                      \
                rs[3][r] += __builtin_amdgcn_exp2f(ac3[r]);                      \
            }                                                                    \
        }                                                                        \
    } while (0)

    // prologue: 2 tiles in flight (nt >= 10 always)
    STAGE(0, 0);
    STAGE(1, 1);

    int t = 0;
    for (; t < nt - 1; ++t) {
        // wait oldest stage (tile t) only; tile t+1 stays in flight
        asm volatile("s_waitcnt vmcnt(2)" ::: "memory");
        __builtin_amdgcn_s_barrier();
        __builtin_amdgcn_sched_barrier(0);
        COMPUTE(t % 3);
        if (t + 2 < nt) STAGE((t + 2) % 3, t + 2);
    }
    asm volatile("s_waitcnt vmcnt(0)" ::: "memory");
    __builtin_amdgcn_s_barrier();
    __builtin_amdgcn_sched_barrier(0);
    COMPUTE(t % 3);

#undef STAGE
#undef COMPUTE

    // reduce row-sums across the 16 column-lanes; write per-split partials
#pragma unroll
    for (int rt = 0; rt < 4; ++rt)
#pragma unroll
        for (int r = 0; r < 4; ++r) {
            float s = rs[rt][r];
            s += __shfl_xor(s, 1);  s += __shfl_xor(s, 2);
            s += __shfl_xor(s, 4);  s += __shfl_xor(s, 8);
            if (lo16 == 0) {
                int row = rowBase + rt * 16 + hi4 * 4 + r;
                partial[blockIdx.y * NROWS + row] = s;
            }
        }
}

// ---- kernel 3: per-row lse - pos, subtract diag, block partial sums --------
__global__ __launch_bounds__(256) void k_finalize(
    const uint16_t* __restrict__ znA, const uint16_t* __restrict__ znB,
    const float* __restrict__ partial, float* __restrict__ blocksum)
{
    int tid = threadIdx.x;
    int i = blockIdx.x * 256 + tid;

    float S = 0.f;
#pragma unroll
    for (int cs = 0; cs < CSPL; ++cs) S += partial[cs * NROWS + i];

    int j = (i + BROWS) & (NROWS - 1);
    const uint4* rAi = (const uint4*)((const char*)znA + (size_t)i * ROWB);
    const uint4* rBi = (const uint4*)((const char*)znB + (size_t)i * ROWB);
    const uint4* rBj = (const uint4*)((const char*)znB + (size_t)j * ROWB);
    float adot = 0.f;   // K1 * <zn_i, zn_j>
    float sdot = 0.f;   // K1 * <zn_i, zn_i>
#pragma unroll
    for (int c = 0; c < 16; ++c) {
        uint4 ua = rAi[c], ub = rBi[c], vb = rBj[c];
        const uint32_t* pa = (const uint32_t*)&ua;
        const uint32_t* pb = (const uint32_t*)&ub;
        const uint32_t* pv = (const uint32_t*)&vb;
#pragma unroll
        for (int q = 0; q < 4; ++q) {
            float a0 = bf2f((uint16_t)(pa[q] & 0xffffu)), a1 = bf2f((uint16_t)(pa[q] >> 16));
            float b0 = bf2f((uint16_t)(pb[q] & 0xffffu)), b1 = bf2f((uint16_t)(pb[q] >> 16));
            float v0 = bf2f((uint16_t)(pv[q] & 0xffffu)), v1 = bf2f((uint16_t)(pv[q] >> 16));
            adot += a0 * v0 + a1 * v1;
            sdot += a0 * b0 + a1 * b1;
        }
    }
    S -= __builtin_amdgcn_exp2f(sdot);                  // remove diagonal term
    float c = LN2F * (__builtin_amdgcn_logf(S) - adot); // ln(S) - pos/T

#pragma unroll
    for (int off = 1; off < 64; off <<= 1) c += __shfl_xor(c, off);
    __shared__ float wsum[4];
    int lane = tid & 63, wid = tid >> 6;
    if (lane == 0) wsum[wid] = c;
    __syncthreads();
    if (tid == 0) blocksum[blockIdx.x] = wsum[0] + wsum[1] + wsum[2] + wsum[3];
}

// ---- kernel 4: final scalar -------------------------------------------------
__global__ __launch_bounds__(64) void k_reduce(
    const float* __restrict__ blocksum, float* __restrict__ out)
{
    int tid = threadIdx.x;
    float v = (tid < 32) ? blocksum[tid] : 0.f;
#pragma unroll
    for (int off = 1; off < 64; off <<= 1) v += __shfl_xor(v, off);
    if (tid == 0) out[0] = v * (1.0f / (float)NROWS);
}

extern "C" void kernel_launch(void* const* d_in, const int* in_sizes, int n_in,
                              void* d_out, int out_size, void* d_ws, size_t ws_size,
                              hipStream_t stream)
{
    const float* zi = (const float*)d_in[0];
    const float* zj = (const float*)d_in[1];
    float* out = (float*)d_out;

    char* ws = (char*)d_ws;
    uint16_t* znA      = (uint16_t*)ws;                                   // 2 MB
    uint16_t* znB      = (uint16_t*)(ws + (size_t)NROWS * ROWB);          // 2 MB
    float*    partial  = (float*)(ws + 2 * (size_t)NROWS * ROWB);         // 768 KB
    float*    blocksum = (float*)(ws + 2 * (size_t)NROWS * ROWB
                                     + (size_t)CSPL * NROWS * 4);

    k_normalize<<<dim3(256), dim3(256), 0, stream>>>(zi, zj, znA, znB);
    k_simlse  <<<dim3(32, CSPL), dim3(256), 0, stream>>>(znA, znB, partial);
    k_finalize<<<dim3(32), dim3(256), 0, stream>>>(znA, znB, partial, blocksum);
    k_reduce  <<<dim3(1), dim3(64), 0, stream>>>(blocksum, out);
}